// Round 17
// baseline (61.194 us; speedup 1.0000x reference)
//
#include <hip/hip_runtime.h>
#include <math.h>

#define NB_TOTAL 65536
#define OUTS 773            // 2 + 514 + 257

typedef float f32x4 __attribute__((ext_vector_type(4)));
typedef float f32x2 __attribute__((ext_vector_type(2)));

// Output row layout (f32):
//  [0..1] x31 | [2+i] G flat i=2j+comp (512 vals) | [514,515] G_o
//  [516+m] h_s | [772] h_o
//
// prm row layout (16 f32):
//  [0]A0 [1]tvs [2]tvc [3]A1 | [4]tc [5]ts [6]x31_0 [7]x31_1
//  [8]Go0 [9]Go1 [10]ho [11]- | [12]C [13]u [14]w [15]pp
//  G0(j) = A0 - tvs*ox + tvc*oy ; G1(j) = A1 + tc*ox + ts*oy
//  h(m)  = C + u*ox + w*oy + pp*q ; q = ox^2+oy^2-R^2
//
// R17 = R14 (proven best, 50.66) with phase A's inner loops rewritten on
// v_pk_fma_f32 (VOP3P packed fp32, 2 FMA/lane/instr — the 157 TF spec is
// the SCALAR rate; packed doubles it; hipcc won't auto-pack).
// pacc stride 33 -> 34 for 8B-aligned ds b64 (2-way bank alias is free).
// R7: only 16B-ALIGNED dwordx4 global stores. R9: one row's chunks in
// flight. R11/R12/R14/R16: A/B overlap is structurally dead — don't retry.

__device__ __forceinline__ int iclamp(int v, int lo, int hi) {
    return v < lo ? lo : (v > hi ? hi : v);
}

__device__ __forceinline__ f32x2 pk_fma(f32x2 a, f32x2 b, f32x2 c) {
    f32x2 d;
    asm("v_pk_fma_f32 %0, %1, %2, %3" : "=v"(d) : "v"(a), "v"(b), "v"(c));
    return d;
}

template<int PH>
__device__ __forceinline__ void phase_rows(
    int blockRow0, int l,
    const float (&prm)[64][16],
    const float* __restrict__ obstacles,
    float* __restrict__ out)
{
    // ---- per-phase obstacle features (registers) --------------------------
    constexpr int aStart = (PH == 0) ? 1 : (PH == 3 ? -1 : 0);
    constexpr int nA = (PH == 0 || PH == 2) ? 2 : 3;

    float Ax[3], Ay[3];
    #pragma unroll
    for (int c = 0; c < nA; ++c) {
        const int j = iclamp(2 * l + aStart + c, 0, 255);
        const float* o = obstacles + (size_t)j * 3;
        Ax[c] = o[0]; Ay[c] = o[1];
    }
    float Bx[3], By[3];
    #pragma unroll
    for (int c = 0; c < nA; ++c) {
        const int j = iclamp(2 * l + 128 + aStart + c, 0, 255);
        const float* o = obstacles + (size_t)j * 3;
        Bx[c] = o[0]; By[c] = o[1];
    }
    float Cx[4], Cy[4], Cq[4];
    #pragma unroll
    for (int c = 0; c < 4; ++c) {
        const int j = iclamp(4 * l - PH + c, 0, 255);
        const float* o = obstacles + (size_t)j * 3;
        const float a = o[0], b = o[1], r = o[2] + 0.6f;  // R = 0.5+rad+0.1
        Cx[c] = a; Cy[c] = b; Cq[c] = fmaf(a, a, b * b) - r * r;
    }
    float o0x = 0.f, o0y = 0.f, e255x = 0.f, e255y = 0.f;
    if (PH == 0 || PH == 1) { o0x = obstacles[0]; o0y = obstacles[1]; }
    if (PH == 3) { e255x = obstacles[255 * 3]; e255y = obstacles[255 * 3 + 1]; }
    float Tx[3], Ty[3], Tq[3];          // h[253..255] features (tail, lane 1)
    if (PH >= 1) {
        #pragma unroll
        for (int c = 0; c < 3; ++c) {
            const float* o = obstacles + (size_t)(253 + c) * 3;
            const float a = o[0], b = o[1], r = o[2] + 0.6f;
            Tx[c] = a; Ty[c] = b; Tq[c] = fmaf(a, a, b * b) - r * r;
        }
    }

    // ---- 16 rows, one per iteration (keep live-set to ONE row) ------------
    #pragma unroll 1
    for (int t = 0; t < 16; ++t) {
        const int rloc = 4 * t + PH;
        const int row  = blockRow0 + rloc;

        const f32x4 c0 = *(const f32x4*)&prm[rloc][0];
        const f32x4 c1 = *(const f32x4*)&prm[rloc][4];
        const f32x4 c2 = *(const f32x4*)&prm[rloc][8];
        const f32x4 c3 = *(const f32x4*)&prm[rloc][12];
        const float A0 = c0.x, tvs = c0.y, tvc = c0.z, A1 = c0.w;
        const float tc = c1.x, ts  = c1.y, x31_0 = c1.z, x31_1 = c1.w;
        const float Go0 = c2.x, Go1 = c2.y, ho = c2.z;
        const float C = c3.x, u = c3.y, w = c3.z, pp = c3.w;

        auto G0 = [&](float X, float Y) { return fmaf(Y, tvc, fmaf(-X, tvs, A0)); };
        auto G1 = [&](float X, float Y) { return fmaf(Y, ts,  fmaf( X, tc,  A1)); };
        auto H  = [&](float X, float Y, float Q) {
            return fmaf(pp, Q, fmaf(w, Y, fmaf(u, X, C)));
        };

        const unsigned base = (unsigned)row * 773u;
        float* a0p = out + (base - (unsigned)PH);        // 16B-aligned

        // chunk A: k = l+1
        f32x4 vA;
        if (PH == 0 || PH == 2)
            vA = (f32x4){G0(Ax[0],Ay[0]), G1(Ax[0],Ay[0]),
                         G0(Ax[1],Ay[1]), G1(Ax[1],Ay[1])};
        else
            vA = (f32x4){G1(Ax[0],Ay[0]), G0(Ax[1],Ay[1]),
                         G1(Ax[1],Ay[1]), G0(Ax[2],Ay[2])};
        if (PH == 3 && l == 0) vA.x = x31_1;             // f=1
        *(f32x4*)(a0p + 4 * (l + 1)) = vA;

        // chunk B: k = l+65
        f32x4 vB;
        if (PH == 0 || PH == 2)
            vB = (f32x4){G0(Bx[0],By[0]), G1(Bx[0],By[0]),
                         G0(Bx[1],By[1]), G1(Bx[1],By[1])};
        else
            vB = (f32x4){G1(Bx[0],By[0]), G0(Bx[1],By[1]),
                         G1(Bx[1],By[1]), G0(Bx[2],By[2])};
        if (l == 63) {                                   // i>=512 -> Go
            if (PH == 0) { vB.z = Go0; vB.w = Go1; }
            if (PH == 1) { vB.w = Go0; }
        }
        *(f32x4*)(a0p + 4 * (l + 65)) = vB;

        // chunk C: k = l+129
        f32x4 vC = (f32x4){H(Cx[0],Cy[0],Cq[0]), H(Cx[1],Cy[1],Cq[1]),
                           H(Cx[2],Cy[2],Cq[2]), H(Cx[3],Cy[3],Cq[3])};
        if (l == 0) {                                    // m<0 -> G511/Go
            if (PH == 1) { vC.x = Go1; }
            if (PH == 2) { vC.x = Go0; vC.y = Go1; }
            if (PH == 3) { vC.x = G1(e255x, e255y); vC.y = Go0; vC.z = Go1; }
        }
        *(f32x4*)(a0p + 4 * (l + 129)) = vC;

        // head chunk k=0 (lane 0): f = t-PH
        if (l == 0) {
            if (PH == 0) {
                *(f32x4*)a0p = (f32x4){x31_0, x31_1, G0(o0x,o0y), G1(o0x,o0y)};
            } else if (PH == 1) {
                a0p[1] = x31_0;
                *(f32x2*)(a0p + 2) = (f32x2){x31_1, G0(o0x,o0y)};
            } else if (PH == 2) {
                *(f32x2*)(a0p + 2) = (f32x2){x31_0, x31_1};
            } else {
                a0p[3] = x31_0;
            }
        }
        // tail chunk k=193 (lane 1): f = 772-PH+t
        else if (l == 1) {
            float* tp = a0p + 772;                       // 16B-aligned
            if (PH == 0) {
                tp[0] = ho;
            } else if (PH == 1) {
                *(f32x2*)tp = (f32x2){H(Tx[2],Ty[2],Tq[2]), ho};
            } else if (PH == 2) {
                *(f32x2*)tp = (f32x2){H(Tx[1],Ty[1],Tq[1]), H(Tx[2],Ty[2],Tq[2])};
                tp[2] = ho;
            } else {
                *(f32x4*)tp = (f32x4){H(Tx[0],Ty[0],Tq[0]), H(Tx[1],Ty[1],Tq[1]),
                                      H(Tx[2],Ty[2],Tq[2]), ho};
            }
        }
    }
}

__global__ __launch_bounds__(256, 2) void fused11(
    const float* __restrict__ x,
    const float* __restrict__ obstacles,
    const float* __restrict__ input_mean, const float* __restrict__ input_std,
    const float* __restrict__ W1,  const float* __restrict__ b1,
    const float* __restrict__ W21, const float* __restrict__ b21,
    const float* __restrict__ W22, const float* __restrict__ b22,
    const float* __restrict__ W31, const float* __restrict__ b31,
    const float* __restrict__ W32, const float* __restrict__ b32,
    float* __restrict__ out)
{
    __shared__ float pacc[2][64][34];   // partial acc exchange (+2 pad: b64 align)
    __shared__ float prm[64][16];       // per-row coefficients

    const int tid  = threadIdx.x;
    const int l    = tid & 63;
    const int wv   = __builtin_amdgcn_readfirstlane(tid >> 6);
    const int role = wv & 1;
    const int half = wv >> 1;
    const int row  = blockIdx.x * 64 + l;

    // ======================= Phase A: MLP (packed fp32) ====================
    float xr[8];
    {
        const float4 xa = *(const float4*)(x + (size_t)row * 8);
        const float4 xb = *(const float4*)(x + (size_t)row * 8 + 4);
        xr[0]=xa.x; xr[1]=xa.y; xr[2]=xa.z; xr[3]=xa.w;
        xr[4]=xb.x; xr[5]=xb.y; xr[6]=xb.z; xr[7]=xb.w;
    }
    f32x2 xd[8];
    #pragma unroll
    for (int k = 0; k < 8; ++k) xd[k] = (f32x2){xr[k], xr[k]};

    const float* Wh = role ? W22 : W21;
    const float* bh = role ? b22 : b21;

    f32x2 acc2[16];
    #pragma unroll
    for (int k2 = 0; k2 < 16; ++k2)
        acc2[k2] = half ? (f32x2){0.0f, 0.0f}
                        : *(const f32x2*)&bh[2 * k2];

    const int ibeg = half * 64;
    #pragma unroll 1
    for (int i0 = ibeg; i0 < ibeg + 64; i0 += 8) {
        // layer-1: 4 hidden-pairs, packed over (u,u+1)
        f32x2 h2[4];
        #pragma unroll
        for (int u2 = 0; u2 < 4; ++u2) {
            f32x2 a2 = *(const f32x2*)&b1[i0 + 2 * u2];
            #pragma unroll
            for (int k = 0; k < 8; ++k) {
                const f32x2 w2 = *(const f32x2*)&W1[k * 128 + i0 + 2 * u2];
                a2 = pk_fma(xd[k], w2, a2);
            }
            h2[u2].x = fmaxf(a2.x, 0.0f);
            h2[u2].y = fmaxf(a2.y, 0.0f);
        }
        // layer-2: packed over acc pairs k2
        #pragma unroll
        for (int u2 = 0; u2 < 4; ++u2) {
            const f32x2 hlo = (f32x2){h2[u2].x, h2[u2].x};
            const f32x2 hhi = (f32x2){h2[u2].y, h2[u2].y};
            const float* wr0 = &Wh[(i0 + 2 * u2) * 32];
            const float* wr1 = &Wh[(i0 + 2 * u2 + 1) * 32];
            #pragma unroll
            for (int k2 = 0; k2 < 16; ++k2) {
                acc2[k2] = pk_fma(hlo, *(const f32x2*)&wr0[2 * k2], acc2[k2]);
                acc2[k2] = pk_fma(hhi, *(const f32x2*)&wr1[2 * k2], acc2[k2]);
            }
        }
    }

    if (half == 0) {
        #pragma unroll
        for (int k2 = 0; k2 < 16; ++k2)
            *(f32x2*)&pacc[role][l][2 * k2] = acc2[k2];
    }
    __syncthreads();

    if (half == 1) {
        #pragma unroll
        for (int k2 = 0; k2 < 16; ++k2) {
            const f32x2 p = *(const f32x2*)&pacc[role][l][2 * k2];
            acc2[k2].x += p.x;
            acc2[k2].y += p.y;
        }

        const float* Wo = role ? W32 : W31;
        const float* bo = role ? b32 : b31;
        float o0 = bo[0], o1 = bo[1];
        #pragma unroll
        for (int k2 = 0; k2 < 16; ++k2) {
            const float a0v = fmaxf(acc2[k2].x, 0.0f);
            const float a1v = fmaxf(acc2[k2].y, 0.0f);
            o0 = fmaf(a0v, Wo[4 * k2 + 0], o0);
            o1 = fmaf(a0v, Wo[4 * k2 + 1], o1);
            o0 = fmaf(a1v, Wo[4 * k2 + 2], o0);
            o1 = fmaf(a1v, Wo[4 * k2 + 3], o1);
        }

        float x0v[8];
        #pragma unroll
        for (int k = 0; k < 8; ++k)
            x0v[k] = fmaf(xr[k], input_std[k], input_mean[k]);
        const float px = x0v[0], py = x0v[1], th = x0v[2], v = x0v[3];
        const float opx = x0v[4], opy = x0v[5], oth = x0v[6], ov = x0v[7];

        float st, ct, sto, cto;
        sincosf(th,  &st,  &ct);
        sincosf(oth, &sto, &cto);

        const float tvs = 2.0f * v * st;
        const float tvc = 2.0f * v * ct;
        const float tc  = 2.0f * ct;
        const float ts  = 2.0f * st;
        const float hc  = 2.0f * v * v;

        const float dxo = px - opx, dyo = py - opy;

        if (role == 0) {
            const float A0  = px * tvs - py * tvc;
            const float A1  = -(px * tc + py * ts);
            const float Go0 = dxo * tvs - dyo * tvc;
            const float Go1 = -(dxo * tc + dyo * ts);
            *(f32x4*)&prm[l][0] = (f32x4){A0, tvs, tvc, A1};
            *(f32x4*)&prm[l][4] = (f32x4){tc, ts, o0, o1};
            *(f32x2*)&prm[l][8] = (f32x2){Go0, Go1};
        } else {
            const float p0 = 4.0f / (1.0f + __expf(-o0));
            const float p1 = 4.0f / (1.0f + __expf(-o1));
            const float ps = p0 + p1;
            const float pp = p0 * p1;
            const float B0 = px * tvc + py * tvs;
            const float C  = hc + ps * B0 + pp * (px * px + py * py);
            const float u  = -(ps * tvc) - 2.0f * pp * px;
            const float w  = -(ps * tvs) - 2.0f * pp * py;
            const float ob  = dxo * dxo + dyo * dyo - 1.21f;     // Ro^2
            const float rvx = v * ct - ov * cto;
            const float rvy = v * st - ov * sto;
            const float obd = 2.0f * (dxo * rvx + dyo * rvy);
            const float cth_sum = ct * cto - st * sto;            // cos(th+oth)
            const float oLf2b = 2.0f * (v * v + ov * ov - 2.0f * v * ov * cth_sum);
            const float ho = oLf2b + ps * obd + pp * ob;
            *(f32x2*)&prm[l][10]  = (f32x2){ho, 0.0f};
            *(f32x4*)&prm[l][12]  = (f32x4){C, u, w, pp};
        }
    }
    __syncthreads();

    // ======================= Phase B: one phase per wave (R14) =============
    const int blockRow0 = blockIdx.x * 64;
    if      (wv == 0) phase_rows<0>(blockRow0, l, prm, obstacles, out);
    else if (wv == 1) phase_rows<1>(blockRow0, l, prm, obstacles, out);
    else if (wv == 2) phase_rows<2>(blockRow0, l, prm, obstacles, out);
    else              phase_rows<3>(blockRow0, l, prm, obstacles, out);
}

extern "C" void kernel_launch(void* const* d_in, const int* in_sizes, int n_in,
                              void* d_out, int out_size, void* d_ws, size_t ws_size,
                              hipStream_t stream) {
    const float* x          = (const float*)d_in[0];
    const float* obstacles  = (const float*)d_in[1];
    const float* input_mean = (const float*)d_in[2];
    const float* input_std  = (const float*)d_in[3];
    const float* W1  = (const float*)d_in[4];
    const float* b1  = (const float*)d_in[5];
    const float* W21 = (const float*)d_in[6];
    const float* b21 = (const float*)d_in[7];
    const float* W22 = (const float*)d_in[8];
    const float* b22 = (const float*)d_in[9];
    const float* W31 = (const float*)d_in[10];
    const float* b31 = (const float*)d_in[11];
    const float* W32 = (const float*)d_in[12];
    const float* b32 = (const float*)d_in[13];

    float* out = (float*)d_out;

    // 1024 blocks x 256 threads, 64 rows/block — R14's proven shape.
    fused11<<<dim3(NB_TOTAL / 64), dim3(256), 0, stream>>>(
        x, obstacles, input_mean, input_std,
        W1, b1, W21, b21, W22, b22, W31, b31, W32, b32, out);
}

// Round 18
// 40.190 us; speedup vs baseline: 1.5226x; 1.5226x over previous
//
#include <hip/hip_runtime.h>
#include <math.h>

#define NB_TOTAL 65536
#define OUTS 773            // 2 + 514 + 257

typedef float f32x4 __attribute__((ext_vector_type(4)));
typedef float f32x2 __attribute__((ext_vector_type(2)));
typedef short short8 __attribute__((ext_vector_type(8)));

// Output row layout (f32):
//  [0..1] x31 | [2+i] G flat i=2j+comp (512 vals) | [514,515] G_o
//  [516+m] h_s | [772] h_o
//
// prm row layout (16 f32):
//  [0]A0 [1]tvs [2]tvc [3]A1 | [4]tc [5]ts [6]x31_0 [7]x31_1
//  [8]Go0 [9]Go1 [10]ho [11]- | [12]C [13]u [14]w [15]pp
//
// R18 = R14's B phase (proven) + MFMA phase A:
//  L1: thread-per-row fp32, waves split k 4-ways (no role redundancy),
//      h -> LDS bf16 (stride 136: 16B-aligned rows, 2-way bank alias only).
//  L2: v_mfma_f32_16x16x32_bf16, 16 MFMAs/wave (branch=wv&1, mbase=(wv>>1)*32),
//      B-fragments preloaded from global W2 (bf16-rounded), bias+relu at C write.
//      k-assignment κ(l,i)=(l>>4)*8+i used consistently for A and B fragments
//      (any bijective κ is correct if consistent); C/D layout is HW-verified:
//      col=lane&15, row=(lane>>4)*4+reg.
//  L3+dynamics: waves 0/1, R14-verbatim, writes prm.
// R7: only 16B-ALIGNED dwordx4 global stores. R9: one row's chunks in flight.
// R17: packed fp32 (v_pk_fma_f32) is NOT a win — do not retry.

__device__ __forceinline__ int iclamp(int v, int lo, int hi) {
    return v < lo ? lo : (v > hi ? hi : v);
}

__device__ __forceinline__ short bf16rn(float f) {
    union { float f; unsigned u; } v; v.f = f;
    const unsigned r = (v.u + 0x7FFFu + ((v.u >> 16) & 1u)) >> 16;
    return (short)r;
}

template<int PH>
__device__ __forceinline__ void phase_rows(
    int blockRow0, int l,
    const float (&prm)[64][16],
    const float* __restrict__ obstacles,
    float* __restrict__ out)
{
    constexpr int aStart = (PH == 0) ? 1 : (PH == 3 ? -1 : 0);
    constexpr int nA = (PH == 0 || PH == 2) ? 2 : 3;

    float Ax[3], Ay[3];
    #pragma unroll
    for (int c = 0; c < nA; ++c) {
        const int j = iclamp(2 * l + aStart + c, 0, 255);
        const float* o = obstacles + (size_t)j * 3;
        Ax[c] = o[0]; Ay[c] = o[1];
    }
    float Bx[3], By[3];
    #pragma unroll
    for (int c = 0; c < nA; ++c) {
        const int j = iclamp(2 * l + 128 + aStart + c, 0, 255);
        const float* o = obstacles + (size_t)j * 3;
        Bx[c] = o[0]; By[c] = o[1];
    }
    float Cx[4], Cy[4], Cq[4];
    #pragma unroll
    for (int c = 0; c < 4; ++c) {
        const int j = iclamp(4 * l - PH + c, 0, 255);
        const float* o = obstacles + (size_t)j * 3;
        const float a = o[0], b = o[1], r = o[2] + 0.6f;  // R = 0.5+rad+0.1
        Cx[c] = a; Cy[c] = b; Cq[c] = fmaf(a, a, b * b) - r * r;
    }
    float o0x = 0.f, o0y = 0.f, e255x = 0.f, e255y = 0.f;
    if (PH == 0 || PH == 1) { o0x = obstacles[0]; o0y = obstacles[1]; }
    if (PH == 3) { e255x = obstacles[255 * 3]; e255y = obstacles[255 * 3 + 1]; }
    float Tx[3], Ty[3], Tq[3];
    if (PH >= 1) {
        #pragma unroll
        for (int c = 0; c < 3; ++c) {
            const float* o = obstacles + (size_t)(253 + c) * 3;
            const float a = o[0], b = o[1], r = o[2] + 0.6f;
            Tx[c] = a; Ty[c] = b; Tq[c] = fmaf(a, a, b * b) - r * r;
        }
    }

    #pragma unroll 1
    for (int t = 0; t < 16; ++t) {
        const int rloc = 4 * t + PH;
        const int row  = blockRow0 + rloc;

        const f32x4 c0 = *(const f32x4*)&prm[rloc][0];
        const f32x4 c1 = *(const f32x4*)&prm[rloc][4];
        const f32x4 c2 = *(const f32x4*)&prm[rloc][8];
        const f32x4 c3 = *(const f32x4*)&prm[rloc][12];
        const float A0 = c0.x, tvs = c0.y, tvc = c0.z, A1 = c0.w;
        const float tc = c1.x, ts  = c1.y, x31_0 = c1.z, x31_1 = c1.w;
        const float Go0 = c2.x, Go1 = c2.y, ho = c2.z;
        const float C = c3.x, u = c3.y, w = c3.z, pp = c3.w;

        auto G0 = [&](float X, float Y) { return fmaf(Y, tvc, fmaf(-X, tvs, A0)); };
        auto G1 = [&](float X, float Y) { return fmaf(Y, ts,  fmaf( X, tc,  A1)); };
        auto H  = [&](float X, float Y, float Q) {
            return fmaf(pp, Q, fmaf(w, Y, fmaf(u, X, C)));
        };

        const unsigned base = (unsigned)row * 773u;
        float* a0p = out + (base - (unsigned)PH);        // 16B-aligned

        f32x4 vA;
        if (PH == 0 || PH == 2)
            vA = (f32x4){G0(Ax[0],Ay[0]), G1(Ax[0],Ay[0]),
                         G0(Ax[1],Ay[1]), G1(Ax[1],Ay[1])};
        else
            vA = (f32x4){G1(Ax[0],Ay[0]), G0(Ax[1],Ay[1]),
                         G1(Ax[1],Ay[1]), G0(Ax[2],Ay[2])};
        if (PH == 3 && l == 0) vA.x = x31_1;             // f=1
        *(f32x4*)(a0p + 4 * (l + 1)) = vA;

        f32x4 vB;
        if (PH == 0 || PH == 2)
            vB = (f32x4){G0(Bx[0],By[0]), G1(Bx[0],By[0]),
                         G0(Bx[1],By[1]), G1(Bx[1],By[1])};
        else
            vB = (f32x4){G1(Bx[0],By[0]), G0(Bx[1],By[1]),
                         G1(Bx[1],By[1]), G0(Bx[2],By[2])};
        if (l == 63) {
            if (PH == 0) { vB.z = Go0; vB.w = Go1; }
            if (PH == 1) { vB.w = Go0; }
        }
        *(f32x4*)(a0p + 4 * (l + 65)) = vB;

        f32x4 vC = (f32x4){H(Cx[0],Cy[0],Cq[0]), H(Cx[1],Cy[1],Cq[1]),
                           H(Cx[2],Cy[2],Cq[2]), H(Cx[3],Cy[3],Cq[3])};
        if (l == 0) {
            if (PH == 1) { vC.x = Go1; }
            if (PH == 2) { vC.x = Go0; vC.y = Go1; }
            if (PH == 3) { vC.x = G1(e255x, e255y); vC.y = Go0; vC.z = Go1; }
        }
        *(f32x4*)(a0p + 4 * (l + 129)) = vC;

        if (l == 0) {
            if (PH == 0) {
                *(f32x4*)a0p = (f32x4){x31_0, x31_1, G0(o0x,o0y), G1(o0x,o0y)};
            } else if (PH == 1) {
                a0p[1] = x31_0;
                *(f32x2*)(a0p + 2) = (f32x2){x31_1, G0(o0x,o0y)};
            } else if (PH == 2) {
                *(f32x2*)(a0p + 2) = (f32x2){x31_0, x31_1};
            } else {
                a0p[3] = x31_0;
            }
        }
        else if (l == 1) {
            float* tp = a0p + 772;                       // 16B-aligned
            if (PH == 0) {
                tp[0] = ho;
            } else if (PH == 1) {
                *(f32x2*)tp = (f32x2){H(Tx[2],Ty[2],Tq[2]), ho};
            } else if (PH == 2) {
                *(f32x2*)tp = (f32x2){H(Tx[1],Ty[1],Tq[1]), H(Tx[2],Ty[2],Tq[2])};
                tp[2] = ho;
            } else {
                *(f32x4*)tp = (f32x4){H(Tx[0],Ty[0],Tq[0]), H(Tx[1],Ty[1],Tq[1]),
                                      H(Tx[2],Ty[2],Tq[2]), ho};
            }
        }
    }
}

#define HS 136              // hmat stride (bf16 elems): 272B rows, 16B-aligned
#define XS 36               // x21 stride (f32): 144B rows, 16B-aligned

__global__ __launch_bounds__(256, 4) void fused12(
    const float* __restrict__ x,
    const float* __restrict__ obstacles,
    const float* __restrict__ input_mean, const float* __restrict__ input_std,
    const float* __restrict__ W1,  const float* __restrict__ b1,
    const float* __restrict__ W21, const float* __restrict__ b21,
    const float* __restrict__ W22, const float* __restrict__ b22,
    const float* __restrict__ W31, const float* __restrict__ b31,
    const float* __restrict__ W32, const float* __restrict__ b32,
    float* __restrict__ out)
{
    __shared__ short hmat[64 * HS];       // 17408 B, bf16 hidden
    __shared__ float x21b[2][64 * XS];    // 18432 B, relu'd layer-2 out
    __shared__ float prm[64][16];         //  4096 B

    const int tid = threadIdx.x;
    const int l   = tid & 63;
    const int wv  = __builtin_amdgcn_readfirstlane(tid >> 6);   // 0..3
    const int blockRow0 = blockIdx.x * 64;
    const int row = blockRow0 + l;

    // ---- B-fragment preload (branch = wv&1); κ(l,i) = (l>>4)*8+i ----------
    const int branch = wv & 1;
    const float* Wb = branch ? W22 : W21;
    short8 bfrag[2][4];
    #pragma unroll
    for (int nt = 0; nt < 2; ++nt) {
        #pragma unroll
        for (int kt = 0; kt < 4; ++kt) {
            short8 f;
            #pragma unroll
            for (int i = 0; i < 8; ++i) {
                const int gi = kt * 32 + (l >> 4) * 8 + i;      // reduction idx
                f[i] = bf16rn(Wb[gi * 32 + nt * 16 + (l & 15)]);
            }
            bfrag[nt][kt] = f;
        }
    }

    // ---- Layer 1: thread-per-row fp32; wave wv computes k in [wv*32,+32) --
    float xr[8];
    {
        const float4 xa = *(const float4*)(x + (size_t)row * 8);
        const float4 xb = *(const float4*)(x + (size_t)row * 8 + 4);
        xr[0]=xa.x; xr[1]=xa.y; xr[2]=xa.z; xr[3]=xa.w;
        xr[4]=xb.x; xr[5]=xb.y; xr[6]=xb.z; xr[7]=xb.w;
    }
    const int kbeg = wv * 32;
    #pragma unroll 1
    for (int g = 0; g < 4; ++g) {
        short8 v8;
        #pragma unroll
        for (int u = 0; u < 8; ++u) {
            const int k = kbeg + g * 8 + u;
            float a = b1[k];
            #pragma unroll
            for (int j = 0; j < 8; ++j)
                a = fmaf(xr[j], W1[j * 128 + k], a);
            v8[u] = bf16rn(fmaxf(a, 0.0f));
        }
        *(short8*)&hmat[l * HS + kbeg + g * 8] = v8;    // 16B-aligned
    }
    __syncthreads();

    // ---- Layer 2: MFMA. branch = wv&1, rows [mbase, mbase+32) -------------
    {
        const int mbase = (wv >> 1) * 32;
        const float* bh = branch ? b22 : b21;
        const float bv0 = bh[l & 15];
        const float bv1 = bh[16 + (l & 15)];
        float* xo = &x21b[branch][0];
        #pragma unroll
        for (int mt = 0; mt < 2; ++mt) {
            f32x4 c0 = {0.f, 0.f, 0.f, 0.f};
            f32x4 c1 = {0.f, 0.f, 0.f, 0.f};
            const int arow = mbase + mt * 16 + (l & 15);
            #pragma unroll
            for (int kt = 0; kt < 4; ++kt) {
                const short8 a = *(const short8*)
                    &hmat[arow * HS + kt * 32 + (l >> 4) * 8];
                c0 = __builtin_amdgcn_mfma_f32_16x16x32_bf16(a, bfrag[0][kt], c0, 0, 0, 0);
                c1 = __builtin_amdgcn_mfma_f32_16x16x32_bf16(a, bfrag[1][kt], c1, 0, 0, 0);
            }
            // C/D: col = lane&15, row = (lane>>4)*4 + reg   [HW-verified]
            const int orow = mbase + mt * 16 + (l >> 4) * 4;
            const int ocol = l & 15;
            #pragma unroll
            for (int j = 0; j < 4; ++j) {
                xo[(orow + j) * XS + ocol]      = fmaxf(c0[j] + bv0, 0.0f);
                xo[(orow + j) * XS + 16 + ocol] = fmaxf(c1[j] + bv1, 0.0f);
            }
        }
    }
    __syncthreads();

    // ---- Layer 3 + dynamics (waves 0,1; R14-verbatim A2) -------------------
    if (wv < 2) {
        const int role = wv;
        float v[32];
        #pragma unroll
        for (int q = 0; q < 8; ++q) {
            const f32x4 t = *(const f32x4*)&x21b[role][l * XS + q * 4];
            v[4*q+0] = t.x; v[4*q+1] = t.y; v[4*q+2] = t.z; v[4*q+3] = t.w;
        }
        const float* Wo = role ? W32 : W31;
        const float* bo = role ? b32 : b31;
        float o0 = bo[0], o1 = bo[1];
        #pragma unroll
        for (int k = 0; k < 32; ++k) {
            o0 = fmaf(v[k], Wo[k * 2 + 0], o0);
            o1 = fmaf(v[k], Wo[k * 2 + 1], o1);
        }

        float x0v[8];
        #pragma unroll
        for (int k = 0; k < 8; ++k)
            x0v[k] = fmaf(xr[k], input_std[k], input_mean[k]);
        const float px = x0v[0], py = x0v[1], th = x0v[2], vv = x0v[3];
        const float opx = x0v[4], opy = x0v[5], oth = x0v[6], ov = x0v[7];

        float st, ct, sto, cto;
        sincosf(th,  &st,  &ct);
        sincosf(oth, &sto, &cto);

        const float tvs = 2.0f * vv * st;
        const float tvc = 2.0f * vv * ct;
        const float tc  = 2.0f * ct;
        const float ts  = 2.0f * st;
        const float hc  = 2.0f * vv * vv;

        const float dxo = px - opx, dyo = py - opy;

        if (role == 0) {
            const float A0  = px * tvs - py * tvc;
            const float A1  = -(px * tc + py * ts);
            const float Go0 = dxo * tvs - dyo * tvc;
            const float Go1 = -(dxo * tc + dyo * ts);
            *(f32x4*)&prm[l][0] = (f32x4){A0, tvs, tvc, A1};
            *(f32x4*)&prm[l][4] = (f32x4){tc, ts, o0, o1};
            *(f32x2*)&prm[l][8] = (f32x2){Go0, Go1};
        } else {
            const float p0 = 4.0f / (1.0f + __expf(-o0));
            const float p1 = 4.0f / (1.0f + __expf(-o1));
            const float ps = p0 + p1;
            const float pp = p0 * p1;
            const float B0 = px * tvc + py * tvs;
            const float C  = hc + ps * B0 + pp * (px * px + py * py);
            const float u  = -(ps * tvc) - 2.0f * pp * px;
            const float w  = -(ps * tvs) - 2.0f * pp * py;
            const float ob  = dxo * dxo + dyo * dyo - 1.21f;     // Ro^2
            const float rvx = vv * ct - ov * cto;
            const float rvy = vv * st - ov * sto;
            const float obd = 2.0f * (dxo * rvx + dyo * rvy);
            const float cth_sum = ct * cto - st * sto;            // cos(th+oth)
            const float oLf2b = 2.0f * (vv * vv + ov * ov - 2.0f * vv * ov * cth_sum);
            const float ho = oLf2b + ps * obd + pp * ob;
            *(f32x2*)&prm[l][10]  = (f32x2){ho, 0.0f};
            *(f32x4*)&prm[l][12]  = (f32x4){C, u, w, pp};
        }
    }
    __syncthreads();

    // ======================= Phase B: one phase per wave (R14) =============
    if      (wv == 0) phase_rows<0>(blockRow0, l, prm, obstacles, out);
    else if (wv == 1) phase_rows<1>(blockRow0, l, prm, obstacles, out);
    else if (wv == 2) phase_rows<2>(blockRow0, l, prm, obstacles, out);
    else              phase_rows<3>(blockRow0, l, prm, obstacles, out);
}

extern "C" void kernel_launch(void* const* d_in, const int* in_sizes, int n_in,
                              void* d_out, int out_size, void* d_ws, size_t ws_size,
                              hipStream_t stream) {
    const float* x          = (const float*)d_in[0];
    const float* obstacles  = (const float*)d_in[1];
    const float* input_mean = (const float*)d_in[2];
    const float* input_std  = (const float*)d_in[3];
    const float* W1  = (const float*)d_in[4];
    const float* b1  = (const float*)d_in[5];
    const float* W21 = (const float*)d_in[6];
    const float* b21 = (const float*)d_in[7];
    const float* W22 = (const float*)d_in[8];
    const float* b22 = (const float*)d_in[9];
    const float* W31 = (const float*)d_in[10];
    const float* b31 = (const float*)d_in[11];
    const float* W32 = (const float*)d_in[12];
    const float* b32 = (const float*)d_in[13];

    float* out = (float*)d_out;

    // 1024 blocks x 256 threads, 64 rows/block — R14's proven shape.
    fused12<<<dim3(NB_TOTAL / 64), dim3(256), 0, stream>>>(
        x, obstacles, input_mean, input_std,
        W1, b1, W21, b21, W22, b22, W31, b31, W32, b32, out);
}